// Round 8
// baseline (500.096 us; speedup 1.0000x reference)
//
#include <hip/hip_runtime.h>

// ---------------------------------------------------------------------------
// GCN 3-layer forward. CSR-gather + bf16 MFMA GEMM, with independent work
// fused into the latency-bound CSR-build kernels (atomic wall hiding).
// d_ws layout (ws proven >= 119.2 MB):
//   [0)      packed: N u64 {hi=count, lo=fixed24 sum(ew)}   (800 KB)
//   [1 MB)   dis: N floats
//   [1.5 MB) flag: 1 int;  [1.5MB+4K) bsums: up to 1024 ints
//   [1.6 MB) row_start: (N+1) ints
//   [2.5 MB) csr: E x int2 {src, norm-as-int}  (12.8 MB, ends 15.3 MB)
//   [15.5MB) Wt1 bf16 [128][128]; Wt2; Wt3 [64][128]
//   [16 MB)  bufA: N*128 bf16 xw (25.6 MB)
//   [42 MB)  hbf: N*128 bf16 (x_bf16, then h1_bf16, then h2_bf16)
//   [96 MB)  eseq: E ints (6.4 MB)
// ---------------------------------------------------------------------------

typedef __attribute__((ext_vector_type(8))) short bf16x8;
typedef __attribute__((ext_vector_type(4))) float f32x4;

__device__ inline unsigned short f2bf(float f) {   // RNE f32 -> bf16
  unsigned int u = __float_as_uint(f);
  u += 0x7fffu + ((u >> 16) & 1u);
  return (unsigned short)(u >> 16);
}

// Block 0: detect int64 edge layout. All blocks: grid-stride zero of packed.
__global__ void init_kernel(const int* __restrict__ ei, int* __restrict__ flag,
                            int* __restrict__ pz, int n) {
  if (blockIdx.x == 0) {
    __shared__ int nonzero;
    if (threadIdx.x == 0) nonzero = 0;
    __syncthreads();
    int acc = 0;
#pragma unroll
    for (int it = 0; it < 8; ++it) {
      const int j = threadIdx.x + (it << 8);
      acc |= ei[2 * j + 1];
    }
    if (acc != 0) atomicOr(&nonzero, 1);
    __syncthreads();
    if (threadIdx.x == 0) flag[0] = (nonzero == 0) ? 1 : 0;
  }
  int i = blockIdx.x * blockDim.x + threadIdx.x;
  const int stride = gridDim.x * blockDim.x;
  for (; i < n; i += stride) pz[i] = 0;
}

// Fused: blocks [0,gE) do the per-edge packed u64 atomic (count+deg, returns
// eseq slot). Blocks [gE,gE+160) transpose+convert W1/W2/W3 to bf16. The rest
// grid-stride convert x to bf16. The atomic blocks are latency-bound at ~1%
// VALU; the prep blocks run in their shadow.
__global__ __launch_bounds__(256)
void count_prep(const int* __restrict__ ei, const int* __restrict__ flag,
                const float* __restrict__ ew, unsigned long long* __restrict__ packed,
                int* __restrict__ eseq, int E, int gE,
                const float* __restrict__ W1, const float* __restrict__ W2,
                const float* __restrict__ W3, unsigned short* __restrict__ Wt1,
                unsigned short* __restrict__ Wt2, unsigned short* __restrict__ Wt3,
                const float* __restrict__ x, unsigned short* __restrict__ xbf,
                long long n4) {
  if (blockIdx.x < gE) {
    const int e = blockIdx.x * 256 + threadIdx.x;
    if (e >= E) return;
    const int use64 = flag[0];
    const int d = use64 ? ei[2 * (E + e)] : ei[E + e];
    const unsigned int fx = (unsigned int)(ew[e] * 16777216.0f);  // 2^24 fixed
    const unsigned long long old =
        atomicAdd(&packed[d], (1ULL << 32) | (unsigned long long)fx);
    eseq[e] = (int)(old >> 32);
    return;
  }
  if (blockIdx.x < gE + 160) {
    const int idx = (blockIdx.x - gE) * 256 + threadIdx.x;
    if (idx < 16384) {
      const int m = idx >> 7, k = idx & 127;
      Wt1[idx] = f2bf(W1[k * 128 + m]);
    } else if (idx < 32768) {
      const int l = idx - 16384;
      const int m = l >> 7, k = l & 127;
      Wt2[l] = f2bf(W2[k * 128 + m]);
    } else {
      const int l = idx - 32768;
      const int m = l >> 7, k = l & 127;
      Wt3[l] = f2bf(W3[k * 64 + m]);
    }
    return;
  }
  long long i = (long long)(blockIdx.x - gE - 160) * 256 + threadIdx.x;
  const long long stride = (long long)(gridDim.x - gE - 160) * 256;
  for (; i < n4; i += stride) {
    const float4 v = ((const float4*)x)[i];
    ushort4 o;
    o.x = f2bf(v.x); o.y = f2bf(v.y); o.z = f2bf(v.z); o.w = f2bf(v.w);
    ((ushort4*)xbf)[i] = o;
  }
}

// ---- 3-phase device-wide exclusive scan over hi words ----
__global__ __launch_bounds__(256)
void scan_phase1(const unsigned long long* __restrict__ packed,
                 int* __restrict__ bsums, int N) {
  __shared__ int red[256];
  const int t = threadIdx.x;
  const int base = blockIdx.x * 1024 + t * 4;
  int s = 0;
#pragma unroll
  for (int j = 0; j < 4; ++j) {
    const int idx = base + j;
    if (idx < N) s += (int)(packed[idx] >> 32);
  }
  red[t] = s;
  __syncthreads();
  for (int off = 128; off > 0; off >>= 1) {
    if (t < off) red[t] += red[t + off];
    __syncthreads();
  }
  if (t == 0) bsums[blockIdx.x] = red[0];
}

__global__ __launch_bounds__(1024)
void scan_phase2(int* __restrict__ bsums, int* __restrict__ row_start, int B, int N) {
  __shared__ int s[1024];
  const int t = threadIdx.x;
  const int v = (t < B) ? bsums[t] : 0;
  s[t] = v;
  __syncthreads();
  for (int off = 1; off < 1024; off <<= 1) {
    const int add = (t >= off) ? s[t - off] : 0;
    __syncthreads();
    s[t] += add;
    __syncthreads();
  }
  if (t < B) bsums[t] = s[t] - v;
  if (t == B - 1) row_start[N] = s[t];
}

// Phase 3 + dis = rsqrt(deg+1) fused.
__global__ __launch_bounds__(256)
void scan_phase3_dis(const unsigned long long* __restrict__ packed,
                     const int* __restrict__ bsums, int* __restrict__ row_start,
                     float* __restrict__ dis, int N) {
  __shared__ int tsum[256];
  const int t = threadIdx.x;
  const int base = blockIdx.x * 1024 + t * 4;
  unsigned long long pk[4];
  int v[4];
#pragma unroll
  for (int j = 0; j < 4; ++j) {
    pk[j] = (base + j < N) ? packed[base + j] : 0ULL;
    v[j] = (int)(pk[j] >> 32);
  }
  const int tot = v[0] + v[1] + v[2] + v[3];
  tsum[t] = tot;
  __syncthreads();
  for (int off = 1; off < 256; off <<= 1) {
    const int add = (t >= off) ? tsum[t - off] : 0;
    __syncthreads();
    tsum[t] += add;
    __syncthreads();
  }
  int run = bsums[blockIdx.x] + tsum[t] - tot;
#pragma unroll
  for (int j = 0; j < 4; ++j) {
    const int idx = base + j;
    if (idx < N) {
      row_start[idx] = run;
      run += v[j];
      const float deg = (float)(unsigned int)pk[j] * (1.0f / 16777216.0f);
      dis[idx] = rsqrtf(deg + 1.0f);
    }
  }
}

// Fused: blocks [0,gE) fill CSR (scatter-bound, low IPC); blocks [gE,..) run
// the independent layer-1 GEMM (hbf @ Wt1 -> bufA) in their shadow.
__global__ __launch_bounds__(256)
void fill_gemm1(const int* __restrict__ ei, const int* __restrict__ flag,
                const float* __restrict__ ew, const float* __restrict__ dis,
                const int* __restrict__ row_start, const int* __restrict__ eseq,
                int2* __restrict__ csr, int E, int gE,
                const unsigned short* __restrict__ A,
                const unsigned short* __restrict__ Bt,
                unsigned short* __restrict__ C, int N) {
  if (blockIdx.x < gE) {
    const int e = blockIdx.x * 256 + threadIdx.x;
    if (e >= E) return;
    const int use64 = flag[0];
    const int s = use64 ? ei[2 * e] : ei[e];
    const int d = use64 ? ei[2 * (E + e)] : ei[E + e];
    const float nm = dis[s] * ew[e] * dis[d];
    const int pos = row_start[d] + eseq[e];
    csr[pos] = make_int2(s, __float_as_int(nm));
    return;
  }
  // layer-1 GEMM, M = 128
  const int bid = blockIdx.x - gE;
  const int lane = threadIdx.x & 63;
  const int m = lane & 15;
  const int q = lane >> 4;
  const int row0 = (bid << 6) + ((threadIdx.x >> 6) << 4);
  const bool rowok = (row0 + m) < N;
  const unsigned short* arow = A + (long long)(row0 + m) * 128 + q * 8;
  bf16x8 a[4];
  const bf16x8 zf = {0, 0, 0, 0, 0, 0, 0, 0};
#pragma unroll
  for (int kt = 0; kt < 4; ++kt)
    a[kt] = rowok ? *(const bf16x8*)(arow + kt * 32) : zf;
#pragma unroll
  for (int ct = 0; ct < 8; ++ct) {
    f32x4 acc = {0.f, 0.f, 0.f, 0.f};
    const unsigned short* brow = Bt + (ct * 16 + m) * 128 + q * 8;
#pragma unroll
    for (int kt = 0; kt < 4; ++kt) {
      const bf16x8 b = *(const bf16x8*)(brow + kt * 32);
      acc = __builtin_amdgcn_mfma_f32_16x16x32_bf16(a[kt], b, acc, 0, 0, 0);
    }
#pragma unroll
    for (int r = 0; r < 4; ++r) {
      const int row = row0 + q * 4 + r;
      if (row < N) C[(long long)row * 128 + ct * 16 + m] = f2bf(acc[r]);
    }
  }
}

// C[N x M] = A[N x 128] @ B[128 x M] via 16x16x32 bf16 MFMA, LDS-free.
template <int M>
__global__ __launch_bounds__(256)
void gemm_mfma(const unsigned short* __restrict__ A, const unsigned short* __restrict__ Bt,
               unsigned short* __restrict__ C, int N) {
  const int lane = threadIdx.x & 63;
  const int m = lane & 15;
  const int q = lane >> 4;
  const int row0 = (blockIdx.x << 6) + ((threadIdx.x >> 6) << 4);

  const bool rowok = (row0 + m) < N;
  const unsigned short* arow = A + (long long)(row0 + m) * 128 + q * 8;
  bf16x8 a[4];
  const bf16x8 zf = {0, 0, 0, 0, 0, 0, 0, 0};
#pragma unroll
  for (int kt = 0; kt < 4; ++kt)
    a[kt] = rowok ? *(const bf16x8*)(arow + kt * 32) : zf;

#pragma unroll
  for (int ct = 0; ct < M / 16; ++ct) {
    f32x4 acc = {0.f, 0.f, 0.f, 0.f};
    const unsigned short* brow = Bt + (ct * 16 + m) * 128 + q * 8;
#pragma unroll
    for (int kt = 0; kt < 4; ++kt) {
      const bf16x8 b = *(const bf16x8*)(brow + kt * 32);
      acc = __builtin_amdgcn_mfma_f32_16x16x32_bf16(a[kt], b, acc, 0, 0, 0);
    }
#pragma unroll
    for (int r = 0; r < 4; ++r) {
      const int row = row0 + q * 4 + r;
      if (row < N) C[(long long)row * M + ct * 16 + m] = f2bf(acc[r]);
    }
  }
}

// One wave per dst node, 8-way edge unroll, wave-uniform (scalar) CSR reads.
template <int M, bool RELU, bool OUTBF>
__global__ __launch_bounds__(256)
void gather(const int2* __restrict__ csr, const int* __restrict__ row_start,
            const unsigned short* __restrict__ xw, const float* __restrict__ dis,
            const float* __restrict__ bias, void* __restrict__ outp, int N) {
  const int node = (blockIdx.x << 2) + (threadIdx.x >> 6);
  const int lane = threadIdx.x & 63;
  if (node >= N) return;
  const int beg = __builtin_amdgcn_readfirstlane(row_start[node]);
  const int end = __builtin_amdgcn_readfirstlane(row_start[node + 1]);
  if (M == 128) {
    const int c = lane << 1;
    float2 a0 = make_float2(0.f, 0.f), a1 = a0, a2 = a0, a3 = a0;
    int e = beg;
    for (; e + 7 < end; e += 8) {
      int2 p[8];
      unsigned int u[8];
#pragma unroll
      for (int j = 0; j < 8; ++j) p[j] = csr[e + j];
#pragma unroll
      for (int j = 0; j < 8; ++j)
        u[j] = *(const unsigned int*)(xw + (long long)p[j].x * 128 + c);
#pragma unroll
      for (int j = 0; j < 8; ++j) {
        const float nm = __int_as_float(p[j].y);
        float2& ac = (j & 4) ? ((j & 2) ? a3 : a2) : ((j & 2) ? a1 : a0);
        ac.x = fmaf(nm, __uint_as_float(u[j] << 16), ac.x);
        ac.y = fmaf(nm, __uint_as_float(u[j] & 0xffff0000u), ac.y);
      }
    }
    for (; e + 1 < end; e += 2) {
      const int2 p0 = csr[e], p1 = csr[e + 1];
      const unsigned int u0 = *(const unsigned int*)(xw + (long long)p0.x * 128 + c);
      const unsigned int u1 = *(const unsigned int*)(xw + (long long)p1.x * 128 + c);
      const float n0 = __int_as_float(p0.y), n1 = __int_as_float(p1.y);
      a0.x = fmaf(n0, __uint_as_float(u0 << 16), a0.x);
      a0.y = fmaf(n0, __uint_as_float(u0 & 0xffff0000u), a0.y);
      a1.x = fmaf(n1, __uint_as_float(u1 << 16), a1.x);
      a1.y = fmaf(n1, __uint_as_float(u1 & 0xffff0000u), a1.y);
    }
    if (e < end) {
      const int2 p = csr[e];
      const float nm = __int_as_float(p.y);
      const unsigned int u = *(const unsigned int*)(xw + (long long)p.x * 128 + c);
      a2.x = fmaf(nm, __uint_as_float(u << 16), a2.x);
      a2.y = fmaf(nm, __uint_as_float(u & 0xffff0000u), a2.y);
    }
    float2 acc;
    acc.x = (a0.x + a1.x) + (a2.x + a3.x);
    acc.y = (a0.y + a1.y) + (a2.y + a3.y);
    const float di = dis[node];
    const float dsq = di * di;
    const unsigned int su = *(const unsigned int*)(xw + (long long)node * 128 + c);
    const float2 bv = *(const float2*)(bias + c);
    acc.x = fmaf(dsq, __uint_as_float(su << 16), acc.x) + bv.x;
    acc.y = fmaf(dsq, __uint_as_float(su & 0xffff0000u), acc.y) + bv.y;
    if (RELU) { acc.x = fmaxf(acc.x, 0.f); acc.y = fmaxf(acc.y, 0.f); }
    if (OUTBF) {
      const unsigned int pk =
          (unsigned int)f2bf(acc.x) | ((unsigned int)f2bf(acc.y) << 16);
      ((unsigned int*)outp)[(long long)node * 64 + lane] = pk;
    } else {
      *(float2*)((float*)outp + (long long)node * 128 + c) = acc;
    }
  } else {
    float a0 = 0.f, a1 = 0.f, a2 = 0.f, a3 = 0.f;
    int e = beg;
    for (; e + 7 < end; e += 8) {
      int2 p[8];
      unsigned int v[8];
#pragma unroll
      for (int j = 0; j < 8; ++j) p[j] = csr[e + j];
#pragma unroll
      for (int j = 0; j < 8; ++j) v[j] = xw[(long long)p[j].x * 64 + lane];
#pragma unroll
      for (int j = 0; j < 8; ++j) {
        float& ac = (j & 4) ? ((j & 2) ? a3 : a2) : ((j & 2) ? a1 : a0);
        ac = fmaf(__int_as_float(p[j].y), __uint_as_float(v[j] << 16), ac);
      }
    }
    for (; e < end; ++e) {
      const int2 p = csr[e];
      const unsigned int v = xw[(long long)p.x * 64 + lane];
      a0 = fmaf(__int_as_float(p.y), __uint_as_float(v << 16), a0);
    }
    float acc = (a0 + a1) + (a2 + a3);
    const float di = dis[node];
    const unsigned int sv = xw[(long long)node * 64 + lane];
    float r = fmaf(di * di, __uint_as_float(sv << 16), acc) + bias[lane];
    if (RELU) r = fmaxf(r, 0.f);
    ((float*)outp)[(long long)node * 64 + lane] = r;
  }
}

extern "C" void kernel_launch(void* const* d_in, const int* in_sizes, int n_in,
                              void* d_out, int out_size, void* d_ws, size_t ws_size,
                              hipStream_t stream) {
  const float* x  = (const float*)d_in[0];
  const int*   ei = (const int*)d_in[1];
  const float* ew = (const float*)d_in[2];
  const float* W1 = (const float*)d_in[3];
  const float* b1 = (const float*)d_in[4];
  const float* W2 = (const float*)d_in[5];
  const float* b2 = (const float*)d_in[6];
  const float* W3 = (const float*)d_in[7];
  const float* b3 = (const float*)d_in[8];
  float* out = (float*)d_out;

  const int IN = 128;
  const int N = in_sizes[0] / IN;   // 100000
  const int E = in_sizes[2];        // 1600000

  char* ws = (char*)d_ws;
  unsigned long long* packed = (unsigned long long*)(ws);
  float* dis       = (float*)(ws + (1u << 20));
  int*   flag      = (int*)(ws + (1536u << 10));
  int*   bsums     = (int*)(ws + (1536u << 10) + 4096);
  int*   row_start = (int*)(ws + (1600u << 10));
  int2*  csr       = (int2*)(ws + (2560u << 10));
  unsigned short* Wt1 = (unsigned short*)(ws + (15872u << 10));
  unsigned short* Wt2 = (unsigned short*)(ws + (15872u << 10) + (128u << 10));
  unsigned short* Wt3 = (unsigned short*)(ws + (15872u << 10) + (256u << 10));
  unsigned short* bufA = (unsigned short*)(ws + (16u << 20));   // bf16 xw
  unsigned short* hbf  = (unsigned short*)(ws + (42u << 20));   // bf16 x / h
  int* eseq = (int*)(ws + (96u << 20));   // 6.4 MB, inside proven footprint

  const dim3 blk(256);
  const int gE = (E + 255) / 256;
  const int B = (N + 1023) / 1024;
  const int gGemm = (N + 63) / 64;
  const int gGather = (N + 3) / 4;

  // --- CSR build + operand prep (fused around the atomic wall) ---
  hipLaunchKernelGGL(init_kernel, dim3(128), blk, 0, stream, ei, flag, (int*)packed, 2 * N);
  hipLaunchKernelGGL(count_prep, dim3(gE + 160 + 1024), blk, 0, stream,
                     ei, flag, ew, packed, eseq, E, gE,
                     W1, W2, W3, Wt1, Wt2, Wt3, x, hbf, (long long)N * 32);
  hipLaunchKernelGGL(scan_phase1, dim3(B), blk, 0, stream, packed, bsums, N);
  hipLaunchKernelGGL(scan_phase2, dim3(1), dim3(1024), 0, stream, bsums, row_start, B, N);
  hipLaunchKernelGGL(scan_phase3_dis, dim3(B), blk, 0, stream, packed, bsums, row_start, dis, N);
  // --- fill CSR fused with independent layer-1 GEMM ---
  hipLaunchKernelGGL(fill_gemm1, dim3(gE + gGemm), blk, 0, stream,
                     ei, flag, ew, dis, row_start, eseq, csr, E, gE,
                     hbf, Wt1, bufA, N);
  // --- layer 1 aggregate ---
  hipLaunchKernelGGL((gather<128, true, true>), dim3(gGather), blk, 0, stream,
                     csr, row_start, bufA, dis, b1, hbf, N);
  // --- layer 2 ---
  hipLaunchKernelGGL((gemm_mfma<128>), dim3(gGemm), blk, 0, stream, hbf, Wt2, bufA, N);
  hipLaunchKernelGGL((gather<128, true, true>), dim3(gGather), blk, 0, stream,
                     csr, row_start, bufA, dis, b2, hbf, N);
  // --- layer 3 ---
  hipLaunchKernelGGL((gemm_mfma<64>), dim3(gGemm), blk, 0, stream, hbf, Wt3, bufA, N);
  hipLaunchKernelGGL((gather<64, false, false>), dim3(gGather), blk, 0, stream,
                     csr, row_start, bufA, dis, b3, out, N);
}

// Round 9
// 493.199 us; speedup vs baseline: 1.0140x; 1.0140x over previous
//
#include <hip/hip_runtime.h>

// ---------------------------------------------------------------------------
// GCN 3-layer forward. CSR-gather + bf16 MFMA GEMM. Independent work fused
// into the latency-bound CSR-build kernels with ROLE INTERLEAVING (blockIdx%k)
// so helper blocks are co-resident with atomic blocks from dispatch start.
// d_ws layout (ws proven >= 119.2 MB):
//   [0)      packed: N u64 {hi=count, lo=fixed24 sum(ew)}   (800 KB)
//   [1 MB)   dis: N floats
//   [1.5 MB) flag: 1 int;  [1.5MB+4K) bsums: up to 1024 ints
//   [1.6 MB) row_start: (N+1) ints
//   [2.5 MB) csr: E x int2 {src, norm-as-int}  (12.8 MB, ends 15.3 MB)
//   [15.5MB) Wt1 bf16 [128][128]; Wt2; Wt3 [64][128]
//   [16 MB)  bufA: N*128 bf16 xw (25.6 MB)
//   [42 MB)  hbf: N*128 bf16 (x_bf16, then h1_bf16, then h2_bf16)
//   [96 MB)  eseq: E ints (6.4 MB)
// ---------------------------------------------------------------------------

typedef __attribute__((ext_vector_type(8))) short bf16x8;
typedef __attribute__((ext_vector_type(4))) float f32x4;

__device__ inline unsigned short f2bf(float f) {   // RNE f32 -> bf16
  unsigned int u = __float_as_uint(f);
  u += 0x7fffu + ((u >> 16) & 1u);
  return (unsigned short)(u >> 16);
}

// Block 0: detect int64 edge layout. All blocks: grid-stride zero of packed.
__global__ void init_kernel(const int* __restrict__ ei, int* __restrict__ flag,
                            int* __restrict__ pz, int n) {
  if (blockIdx.x == 0) {
    __shared__ int nonzero;
    if (threadIdx.x == 0) nonzero = 0;
    __syncthreads();
    int acc = 0;
#pragma unroll
    for (int it = 0; it < 8; ++it) {
      const int j = threadIdx.x + (it << 8);
      acc |= ei[2 * j + 1];
    }
    if (acc != 0) atomicOr(&nonzero, 1);
    __syncthreads();
    if (threadIdx.x == 0) flag[0] = (nonzero == 0) ? 1 : 0;
  }
  int i = blockIdx.x * blockDim.x + threadIdx.x;
  const int stride = gridDim.x * blockDim.x;
  for (; i < n; i += stride) pz[i] = 0;
}

// Interleaved: blocks with r%6==5 are prep (W transpose->bf16, x->bf16);
// the other 5/6 do the per-edge packed u64 atomic. P = prep block count.
__global__ __launch_bounds__(256)
void count_prep(const int* __restrict__ ei, const int* __restrict__ flag,
                const float* __restrict__ ew, unsigned long long* __restrict__ packed,
                int* __restrict__ eseq, int E, int P,
                const float* __restrict__ W1, const float* __restrict__ W2,
                const float* __restrict__ W3, unsigned short* __restrict__ Wt1,
                unsigned short* __restrict__ Wt2, unsigned short* __restrict__ Wt3,
                const float* __restrict__ x, unsigned short* __restrict__ xbf,
                long long n4) {
  const int r = blockIdx.x;
  if ((r % 6) != 5) {   // atomic role
    const int aid = r - (r + 1) / 6;
    const int e = aid * 256 + threadIdx.x;
    if (e >= E) return;
    const int use64 = flag[0];
    const int d = use64 ? ei[2 * (E + e)] : ei[E + e];
    const unsigned int fx = (unsigned int)(ew[e] * 16777216.0f);  // 2^24 fixed
    const unsigned long long old =
        atomicAdd(&packed[d], (1ULL << 32) | (unsigned long long)fx);
    eseq[e] = (int)(old >> 32);
    return;
  }
  const int pid = r / 6;   // 0..P-1
  if (pid < 160) {         // weight transpose+convert (40960 elems)
    const int idx = pid * 256 + threadIdx.x;
    if (idx < 16384) {
      const int m = idx >> 7, k = idx & 127;
      Wt1[idx] = f2bf(W1[k * 128 + m]);
    } else if (idx < 32768) {
      const int l = idx - 16384;
      const int m = l >> 7, k = l & 127;
      Wt2[l] = f2bf(W2[k * 128 + m]);
    } else {
      const int l = idx - 32768;
      const int m = l >> 7, k = l & 127;
      Wt3[l] = f2bf(W3[k * 64 + m]);
    }
    return;
  }
  long long i = (long long)(pid - 160) * 256 + threadIdx.x;
  const long long stride = (long long)(P - 160) * 256;
  for (; i < n4; i += stride) {
    const float4 v = ((const float4*)x)[i];
    ushort4 o;
    o.x = f2bf(v.x); o.y = f2bf(v.y); o.z = f2bf(v.z); o.w = f2bf(v.w);
    ((ushort4*)xbf)[i] = o;
  }
}

// ---- 3-phase device-wide exclusive scan over hi words ----
__global__ __launch_bounds__(256)
void scan_phase1(const unsigned long long* __restrict__ packed,
                 int* __restrict__ bsums, int N) {
  __shared__ int red[256];
  const int t = threadIdx.x;
  const int base = blockIdx.x * 1024 + t * 4;
  int s = 0;
#pragma unroll
  for (int j = 0; j < 4; ++j) {
    const int idx = base + j;
    if (idx < N) s += (int)(packed[idx] >> 32);
  }
  red[t] = s;
  __syncthreads();
  for (int off = 128; off > 0; off >>= 1) {
    if (t < off) red[t] += red[t + off];
    __syncthreads();
  }
  if (t == 0) bsums[blockIdx.x] = red[0];
}

__global__ __launch_bounds__(1024)
void scan_phase2(int* __restrict__ bsums, int* __restrict__ row_start, int B, int N) {
  __shared__ int s[1024];
  const int t = threadIdx.x;
  const int v = (t < B) ? bsums[t] : 0;
  s[t] = v;
  __syncthreads();
  for (int off = 1; off < 1024; off <<= 1) {
    const int add = (t >= off) ? s[t - off] : 0;
    __syncthreads();
    s[t] += add;
    __syncthreads();
  }
  if (t < B) bsums[t] = s[t] - v;
  if (t == B - 1) row_start[N] = s[t];
}

// Phase 3 + dis = rsqrt(deg+1) fused.
__global__ __launch_bounds__(256)
void scan_phase3_dis(const unsigned long long* __restrict__ packed,
                     const int* __restrict__ bsums, int* __restrict__ row_start,
                     float* __restrict__ dis, int N) {
  __shared__ int tsum[256];
  const int t = threadIdx.x;
  const int base = blockIdx.x * 1024 + t * 4;
  unsigned long long pk[4];
  int v[4];
#pragma unroll
  for (int j = 0; j < 4; ++j) {
    pk[j] = (base + j < N) ? packed[base + j] : 0ULL;
    v[j] = (int)(pk[j] >> 32);
  }
  const int tot = v[0] + v[1] + v[2] + v[3];
  tsum[t] = tot;
  __syncthreads();
  for (int off = 1; off < 256; off <<= 1) {
    const int add = (t >= off) ? tsum[t - off] : 0;
    __syncthreads();
    tsum[t] += add;
    __syncthreads();
  }
  int run = bsums[blockIdx.x] + tsum[t] - tot;
#pragma unroll
  for (int j = 0; j < 4; ++j) {
    const int idx = base + j;
    if (idx < N) {
      row_start[idx] = run;
      run += v[j];
      const float deg = (float)(unsigned int)pk[j] * (1.0f / 16777216.0f);
      dis[idx] = rsqrtf(deg + 1.0f);
    }
  }
}

// Interleaved: blocks with r%5==4 (and r/5 < G) run the layer-1 GEMM; the
// rest fill the CSR (scatter-bound). Co-resident from dispatch start.
__global__ __launch_bounds__(256)
void fill_gemm1(const int* __restrict__ ei, const int* __restrict__ flag,
                const float* __restrict__ ew, const float* __restrict__ dis,
                const int* __restrict__ row_start, const int* __restrict__ eseq,
                int2* __restrict__ csr, int E, int G,
                const unsigned short* __restrict__ A,
                const unsigned short* __restrict__ Bt,
                unsigned short* __restrict__ C, int N) {
  const int r = blockIdx.x;
  const bool gemm_role = ((r % 5) == 4) && (r / 5 < G);
  if (!gemm_role) {
    const int aid = r - ((r + 1) / 5 < G ? (r + 1) / 5 : G);
    const int e = aid * 256 + threadIdx.x;
    if (e >= E) return;
    const int use64 = flag[0];
    const int s = use64 ? ei[2 * e] : ei[e];
    const int d = use64 ? ei[2 * (E + e)] : ei[E + e];
    const float nm = dis[s] * ew[e] * dis[d];
    const int pos = row_start[d] + eseq[e];
    csr[pos] = make_int2(s, __float_as_int(nm));
    return;
  }
  // layer-1 GEMM, M = 128
  const int bid = r / 5;
  const int lane = threadIdx.x & 63;
  const int m = lane & 15;
  const int q = lane >> 4;
  const int row0 = (bid << 6) + ((threadIdx.x >> 6) << 4);
  const bool rowok = (row0 + m) < N;
  const unsigned short* arow = A + (long long)(row0 + m) * 128 + q * 8;
  bf16x8 a[4];
  const bf16x8 zf = {0, 0, 0, 0, 0, 0, 0, 0};
#pragma unroll
  for (int kt = 0; kt < 4; ++kt)
    a[kt] = rowok ? *(const bf16x8*)(arow + kt * 32) : zf;
#pragma unroll
  for (int ct = 0; ct < 8; ++ct) {
    f32x4 acc = {0.f, 0.f, 0.f, 0.f};
    const unsigned short* brow = Bt + (ct * 16 + m) * 128 + q * 8;
#pragma unroll
    for (int kt = 0; kt < 4; ++kt) {
      const bf16x8 b = *(const bf16x8*)(brow + kt * 32);
      acc = __builtin_amdgcn_mfma_f32_16x16x32_bf16(a[kt], b, acc, 0, 0, 0);
    }
#pragma unroll
    for (int r2 = 0; r2 < 4; ++r2) {
      const int row = row0 + q * 4 + r2;
      if (row < N) C[(long long)row * 128 + ct * 16 + m] = f2bf(acc[r2]);
    }
  }
}

// C[N x M] = A[N x 128] @ B[128 x M] via 16x16x32 bf16 MFMA, LDS-free.
template <int M>
__global__ __launch_bounds__(256)
void gemm_mfma(const unsigned short* __restrict__ A, const unsigned short* __restrict__ Bt,
               unsigned short* __restrict__ C, int N) {
  const int lane = threadIdx.x & 63;
  const int m = lane & 15;
  const int q = lane >> 4;
  const int row0 = (blockIdx.x << 6) + ((threadIdx.x >> 6) << 4);

  const bool rowok = (row0 + m) < N;
  const unsigned short* arow = A + (long long)(row0 + m) * 128 + q * 8;
  bf16x8 a[4];
  const bf16x8 zf = {0, 0, 0, 0, 0, 0, 0, 0};
#pragma unroll
  for (int kt = 0; kt < 4; ++kt)
    a[kt] = rowok ? *(const bf16x8*)(arow + kt * 32) : zf;

#pragma unroll
  for (int ct = 0; ct < M / 16; ++ct) {
    f32x4 acc = {0.f, 0.f, 0.f, 0.f};
    const unsigned short* brow = Bt + (ct * 16 + m) * 128 + q * 8;
#pragma unroll
    for (int kt = 0; kt < 4; ++kt) {
      const bf16x8 b = *(const bf16x8*)(brow + kt * 32);
      acc = __builtin_amdgcn_mfma_f32_16x16x32_bf16(a[kt], b, acc, 0, 0, 0);
    }
#pragma unroll
    for (int r = 0; r < 4; ++r) {
      const int row = row0 + q * 4 + r;
      if (row < N) C[(long long)row * M + ct * 16 + m] = f2bf(acc[r]);
    }
  }
}

// One wave per dst node, 8-way edge unroll, wave-uniform (scalar) CSR reads.
template <int M, bool RELU, bool OUTBF>
__global__ __launch_bounds__(256)
void gather(const int2* __restrict__ csr, const int* __restrict__ row_start,
            const unsigned short* __restrict__ xw, const float* __restrict__ dis,
            const float* __restrict__ bias, void* __restrict__ outp, int N) {
  const int node = (blockIdx.x << 2) + (threadIdx.x >> 6);
  const int lane = threadIdx.x & 63;
  if (node >= N) return;
  const int beg = __builtin_amdgcn_readfirstlane(row_start[node]);
  const int end = __builtin_amdgcn_readfirstlane(row_start[node + 1]);
  if (M == 128) {
    const int c = lane << 1;
    float2 a0 = make_float2(0.f, 0.f), a1 = a0, a2 = a0, a3 = a0;
    int e = beg;
    for (; e + 7 < end; e += 8) {
      int2 p[8];
      unsigned int u[8];
#pragma unroll
      for (int j = 0; j < 8; ++j) p[j] = csr[e + j];
#pragma unroll
      for (int j = 0; j < 8; ++j)
        u[j] = *(const unsigned int*)(xw + (long long)p[j].x * 128 + c);
#pragma unroll
      for (int j = 0; j < 8; ++j) {
        const float nm = __int_as_float(p[j].y);
        float2& ac = (j & 4) ? ((j & 2) ? a3 : a2) : ((j & 2) ? a1 : a0);
        ac.x = fmaf(nm, __uint_as_float(u[j] << 16), ac.x);
        ac.y = fmaf(nm, __uint_as_float(u[j] & 0xffff0000u), ac.y);
      }
    }
    for (; e + 1 < end; e += 2) {
      const int2 p0 = csr[e], p1 = csr[e + 1];
      const unsigned int u0 = *(const unsigned int*)(xw + (long long)p0.x * 128 + c);
      const unsigned int u1 = *(const unsigned int*)(xw + (long long)p1.x * 128 + c);
      const float n0 = __int_as_float(p0.y), n1 = __int_as_float(p1.y);
      a0.x = fmaf(n0, __uint_as_float(u0 << 16), a0.x);
      a0.y = fmaf(n0, __uint_as_float(u0 & 0xffff0000u), a0.y);
      a1.x = fmaf(n1, __uint_as_float(u1 << 16), a1.x);
      a1.y = fmaf(n1, __uint_as_float(u1 & 0xffff0000u), a1.y);
    }
    if (e < end) {
      const int2 p = csr[e];
      const float nm = __int_as_float(p.y);
      const unsigned int u = *(const unsigned int*)(xw + (long long)p.x * 128 + c);
      a2.x = fmaf(nm, __uint_as_float(u << 16), a2.x);
      a2.y = fmaf(nm, __uint_as_float(u & 0xffff0000u), a2.y);
    }
    float2 acc;
    acc.x = (a0.x + a1.x) + (a2.x + a3.x);
    acc.y = (a0.y + a1.y) + (a2.y + a3.y);
    const float di = dis[node];
    const float dsq = di * di;
    const unsigned int su = *(const unsigned int*)(xw + (long long)node * 128 + c);
    const float2 bv = *(const float2*)(bias + c);
    acc.x = fmaf(dsq, __uint_as_float(su << 16), acc.x) + bv.x;
    acc.y = fmaf(dsq, __uint_as_float(su & 0xffff0000u), acc.y) + bv.y;
    if (RELU) { acc.x = fmaxf(acc.x, 0.f); acc.y = fmaxf(acc.y, 0.f); }
    if (OUTBF) {
      const unsigned int pk =
          (unsigned int)f2bf(acc.x) | ((unsigned int)f2bf(acc.y) << 16);
      ((unsigned int*)outp)[(long long)node * 64 + lane] = pk;
    } else {
      *(float2*)((float*)outp + (long long)node * 128 + c) = acc;
    }
  } else {
    float a0 = 0.f, a1 = 0.f, a2 = 0.f, a3 = 0.f;
    int e = beg;
    for (; e + 7 < end; e += 8) {
      int2 p[8];
      unsigned int v[8];
#pragma unroll
      for (int j = 0; j < 8; ++j) p[j] = csr[e + j];
#pragma unroll
      for (int j = 0; j < 8; ++j) v[j] = xw[(long long)p[j].x * 64 + lane];
#pragma unroll
      for (int j = 0; j < 8; ++j) {
        float& ac = (j & 4) ? ((j & 2) ? a3 : a2) : ((j & 2) ? a1 : a0);
        ac = fmaf(__int_as_float(p[j].y), __uint_as_float(v[j] << 16), ac);
      }
    }
    for (; e < end; ++e) {
      const int2 p = csr[e];
      const unsigned int v = xw[(long long)p.x * 64 + lane];
      a0 = fmaf(__int_as_float(p.y), __uint_as_float(v << 16), a0);
    }
    float acc = (a0 + a1) + (a2 + a3);
    const float di = dis[node];
    const unsigned int sv = xw[(long long)node * 64 + lane];
    float r = fmaf(di * di, __uint_as_float(sv << 16), acc) + bias[lane];
    if (RELU) r = fmaxf(r, 0.f);
    ((float*)outp)[(long long)node * 64 + lane] = r;
  }
}

extern "C" void kernel_launch(void* const* d_in, const int* in_sizes, int n_in,
                              void* d_out, int out_size, void* d_ws, size_t ws_size,
                              hipStream_t stream) {
  const float* x  = (const float*)d_in[0];
  const int*   ei = (const int*)d_in[1];
  const float* ew = (const float*)d_in[2];
  const float* W1 = (const float*)d_in[3];
  const float* b1 = (const float*)d_in[4];
  const float* W2 = (const float*)d_in[5];
  const float* b2 = (const float*)d_in[6];
  const float* W3 = (const float*)d_in[7];
  const float* b3 = (const float*)d_in[8];
  float* out = (float*)d_out;

  const int IN = 128;
  const int N = in_sizes[0] / IN;   // 100000
  const int E = in_sizes[2];        // 1600000

  char* ws = (char*)d_ws;
  unsigned long long* packed = (unsigned long long*)(ws);
  float* dis       = (float*)(ws + (1u << 20));
  int*   flag      = (int*)(ws + (1536u << 10));
  int*   bsums     = (int*)(ws + (1536u << 10) + 4096);
  int*   row_start = (int*)(ws + (1600u << 10));
  int2*  csr       = (int2*)(ws + (2560u << 10));
  unsigned short* Wt1 = (unsigned short*)(ws + (15872u << 10));
  unsigned short* Wt2 = (unsigned short*)(ws + (15872u << 10) + (128u << 10));
  unsigned short* Wt3 = (unsigned short*)(ws + (15872u << 10) + (256u << 10));
  unsigned short* bufA = (unsigned short*)(ws + (16u << 20));   // bf16 xw
  unsigned short* hbf  = (unsigned short*)(ws + (42u << 20));   // bf16 x / h
  int* eseq = (int*)(ws + (96u << 20));   // 6.4 MB

  const dim3 blk(256);
  const int gE = (E + 255) / 256;            // 6250 atomic/fill blocks
  const int B = (N + 1023) / 1024;
  const int gGemm = (N + 63) / 64;           // 1563
  const int gGather = (N + 3) / 4;

  // count_prep: P prep blocks interleaved every 6th slot; 5/6 atomic blocks.
  const int P = (gE + 4) / 5;                // 1250 >= 160 + conv blocks
  const int T1 = 6 * P;                      // atomic blocks = T1 - P = 6250
  // fill_gemm1: gGemm gemm blocks every 5th slot; 4/5 fill blocks.
  const int T2 = 5 * gGemm;                  // fill blocks = 4*gGemm >= gE

  // --- CSR build + operand prep (interleaved around the atomic wall) ---
  hipLaunchKernelGGL(init_kernel, dim3(128), blk, 0, stream, ei, flag, (int*)packed, 2 * N);
  hipLaunchKernelGGL(count_prep, dim3(T1), blk, 0, stream,
                     ei, flag, ew, packed, eseq, E, P,
                     W1, W2, W3, Wt1, Wt2, Wt3, x, hbf, (long long)N * 32);
  hipLaunchKernelGGL(scan_phase1, dim3(B), blk, 0, stream, packed, bsums, N);
  hipLaunchKernelGGL(scan_phase2, dim3(1), dim3(1024), 0, stream, bsums, row_start, B, N);
  hipLaunchKernelGGL(scan_phase3_dis, dim3(B), blk, 0, stream, packed, bsums, row_start, dis, N);
  // --- fill CSR interleaved with independent layer-1 GEMM ---
  hipLaunchKernelGGL(fill_gemm1, dim3(T2), blk, 0, stream,
                     ei, flag, ew, dis, row_start, eseq, csr, E, gGemm,
                     hbf, Wt1, bufA, N);
  // --- layer 1 aggregate ---
  hipLaunchKernelGGL((gather<128, true, true>), dim3(gGather), blk, 0, stream,
                     csr, row_start, bufA, dis, b1, hbf, N);
  // --- layer 2 ---
  hipLaunchKernelGGL((gemm_mfma<128>), dim3(gGemm), blk, 0, stream, hbf, Wt2, bufA, N);
  hipLaunchKernelGGL((gather<128, true, true>), dim3(gGather), blk, 0, stream,
                     csr, row_start, bufA, dis, b2, hbf, N);
  // --- layer 3 ---
  hipLaunchKernelGGL((gemm_mfma<64>), dim3(gGemm), blk, 0, stream, hbf, Wt3, bufA, N);
  hipLaunchKernelGGL((gather<64, false, false>), dim3(gGather), blk, 0, stream,
                     csr, row_start, bufA, dis, b3, out, N);
}